// Round 7
// baseline (141.621 us; speedup 1.0000x reference)
//
#include <hip/hip_runtime.h>

typedef unsigned short u16;
typedef unsigned int u32;
typedef __attribute__((ext_vector_type(8))) short bf16x8;   // 8 bf16 = 4 VGPR
typedef __attribute__((ext_vector_type(4))) float f32x4;

#define CH   256
#define KKG  144
#define HW   4096
#define CSP  68     // u16 stride for ker dump in LDS (64 + 4 pad)
#define CHS  538    // u16 LDS stride per channel in prep (8*66 + 10, odd dword count)

__device__ __forceinline__ u16 f2bf(float f) {               // RNE float->bf16
    u32 u = __float_as_uint(f);
    u += 0x7FFFu + ((u >> 16) & 1u);
    return (u16)(u >> 16);
}
__device__ __forceinline__ float bf2f(u16 u) {
    return __uint_as_float(((u32)u) << 16);
}

// ---------------- Kernel A: Mfrag = bf16(W_span @ W_reduce) in A-frag-linear order
// Mfrag[ks(8)][mt(9)][lane(64)][8]; bias fused.
__global__ __launch_bounds__(256) void fuse_weights_k(
    const float* __restrict__ Wr, const float* __restrict__ br,
    const float* __restrict__ Ws, const float* __restrict__ bs,
    u16* __restrict__ Mfrag, float* __restrict__ biasF)
{
    __shared__ float ws[128];
    const int r = blockIdx.x;    // 0..143 (ker row)
    const int c = threadIdx.x;   // 0..255 (channel = K)
    if (c < 128) ws[c] = Ws[r * 128 + c];
    __syncthreads();
    float acc = 0.f;
#pragma unroll 8
    for (int o = 0; o < 128; ++o) acc += ws[o] * Wr[o * CH + c];
    const int ks = c >> 5, quad = (c >> 3) & 3, jj = c & 7;
    const int mt = r >> 4, lane = (r & 15) + (quad << 4);
    Mfrag[((ks * 9 + mt) * 64 + lane) * 8 + jj] = f2bf(acc);
    if (c == 0) {
        float bb = bs[r];
        for (int o = 0; o < 128; ++o) bb += ws[o] * br[o];
        biasF[r] = bb;
    }
}

// ---------------- Kernel P: prep — read x once, emit:
//  Xc8[b][ks(8)][col(4096)][quad(4)][jj(8)]  (bf16; stage-1 B-frag = 1 contiguous 16B)
//  XT [b][ch(256)][j(64)][m(64)]             (bf16; stage-2 B-frag = 1 contiguous 16B)
// block = (b, cc: 32-ch chunk, mo: 8-row chunk) = 8*8*8 = 512 blocks
__global__ __launch_bounds__(256) void prep_k(
    const float* __restrict__ x, u16* __restrict__ Xc8, u16* __restrict__ XT)
{
    __shared__ u16 L[32 * CHS];          // 34432 B, elem(ch, r, j) = ch*CHS + r*66 + j
    const int blk = blockIdx.x;
    const int b = blk >> 6, cc = (blk >> 3) & 7, mo = blk & 7;
    const int t = threadIdx.x;

    // load 32ch x 8r x 64j as float4, convert, store LDS
#pragma unroll
    for (int q = 0; q < 16; ++q) {
        const int idx = q * 256 + t;
        const int c4 = idx & 15, r = (idx >> 4) & 7, ch = idx >> 7;
        const float4 v = *(const float4*)(x + ((size_t)(b * CH + cc * 32 + ch)) * HW
                                            + (mo * 8 + r) * 64 + c4 * 4);
        u16* dst = L + ch * CHS + r * 66 + c4 * 4;
        dst[0] = f2bf(v.x); dst[1] = f2bf(v.y); dst[2] = f2bf(v.z); dst[3] = f2bf(v.w);
    }
    __syncthreads();

    // Xc8: chunks (r, j, quad): value[jj] = L[(quad*8+jj)][r][j]
#pragma unroll
    for (int q = 0; q < 8; ++q) {
        const int idx = q * 256 + t;
        const int quad = idx & 3, j = (idx >> 2) & 63, r = idx >> 8;
        u16 h[8];
#pragma unroll
        for (int jj = 0; jj < 8; ++jj) h[jj] = L[(quad * 8 + jj) * CHS + r * 66 + j];
        uint4 pk;
        pk.x = (u32)h[0] | ((u32)h[1] << 16);
        pk.y = (u32)h[2] | ((u32)h[3] << 16);
        pk.z = (u32)h[4] | ((u32)h[5] << 16);
        pk.w = (u32)h[6] | ((u32)h[7] << 16);
        const size_t col = (size_t)(mo * 8 + r) * 64 + j;
        *(uint4*)(Xc8 + ((size_t)(b * 8 + cc) * HW + col) * 32 + quad * 8) = pk;
    }

    // XT: chunks (ch, j): value[r] = L[ch][r][j] -> XT[b][cc*32+ch][j][mo*8 + r]
#pragma unroll
    for (int q = 0; q < 8; ++q) {
        const int idx = q * 256 + t;
        const int j = idx & 63, ch = idx >> 6;
        u16 h[8];
#pragma unroll
        for (int r = 0; r < 8; ++r) h[r] = L[ch * CHS + r * 66 + j];
        uint4 pk;
        pk.x = (u32)h[0] | ((u32)h[1] << 16);
        pk.y = (u32)h[2] | ((u32)h[3] << 16);
        pk.z = (u32)h[4] | ((u32)h[5] << 16);
        pk.w = (u32)h[6] | ((u32)h[7] << 16);
        *(uint4*)(XT + ((size_t)(b * CH + cc * 32 + ch)) * HW + j * 64 + mo * 8) = pk;
    }
}

// ---------------- Kernel B: per (b, image row): ker[144][64] = M @ X + bias via MFMA
// (B-frags = single 16B loads from Xc8), then ki-shift recombine ->
// Afrag[bg][ks(6)][mt(4)][lane][8]
__global__ __launch_bounds__(256, 4) void ker_abar_k(
    const u16* __restrict__ Xc8, const u16* __restrict__ Mfrag,
    const float* __restrict__ biasF, u16* __restrict__ Afrag)
{
    __shared__ u16 Cs[KKG * CSP];      // 19584 B
    __shared__ float bias_s[KKG];
    const int b = blockIdx.x >> 6, irow = blockIdx.x & 63;
    const int t = threadIdx.x, lane = t & 63, w = t >> 6;
    const int nl = lane & 15, quad = lane >> 4;
    if (t < KKG) bias_s[t] = biasF[t];

    f32x4 acc[9];
#pragma unroll
    for (int mt = 0; mt < 9; ++mt) acc[mt] = (f32x4)0.f;

    const size_t ncol = (size_t)irow * 64 + w * 16 + nl;
#pragma unroll
    for (int ks = 0; ks < 8; ++ks) {
        const bf16x8 bv = *(const bf16x8*)(Xc8 + ((size_t)(b * 8 + ks) * HW + ncol) * 32 + quad * 8);
        const bf16x8* Ag = ((const bf16x8*)Mfrag) + (ks * 9) * 64 + lane;
#pragma unroll
        for (int mt = 0; mt < 9; ++mt)
            acc[mt] = __builtin_amdgcn_mfma_f32_16x16x32_bf16(Ag[mt * 64], bv, acc[mt], 0, 0, 0);
    }
    __syncthreads();   // bias_s visible
    // dump ker = C + bias (D layout: col = lane&15, row = quad*4+reg)
#pragma unroll
    for (int mt = 0; mt < 9; ++mt) {
        const int rb = mt * 16 + quad * 4;
#pragma unroll
        for (int reg = 0; reg < 4; ++reg)
            Cs[(rb + reg) * CSP + w * 16 + nl] = f2bf(acc[mt][reg] + bias_s[rb + reg]);
    }
    __syncthreads();
    // Abar recombine + frag-linear store: 48 gd x 8 octs = 384 16B-chunks
    for (int v = t; v < 384; v += 256) {
        const int gd = v >> 3, o = v & 7;
        const int g = gd / 3, d = gd - g * 3;
        const int r0 = g * 9 + d;
        u16 h[8];
#pragma unroll
        for (int e = 0; e < 8; ++e) {
            const int m = o * 8 + e;
            float s = bf2f(Cs[(r0 + 3) * CSP + m]);            // ki=1
            if (m < 63) s += bf2f(Cs[r0 * CSP + m + 1]);       // ki=0 -> col+1
            if (m > 0)  s += bf2f(Cs[(r0 + 6) * CSP + m - 1]); // ki=2 -> col-1
            h[e] = f2bf(s);
        }
        uint4 pk;
        pk.x = (u32)h[0] | ((u32)h[1] << 16);
        pk.y = (u32)h[2] | ((u32)h[3] << 16);
        pk.z = (u32)h[4] | ((u32)h[5] << 16);
        pk.w = (u32)h[6] | ((u32)h[7] << 16);
        const int ks2 = 2 * d + (o >> 2), quad2 = o & 3;
        const int mt2 = irow >> 4, lane2 = (irow & 15) + (quad2 << 4);
        const size_t idx = ((((size_t)(b * 16 + g) * 6 + ks2) * 4 + mt2) * 64 + lane2) * 8;
        *(uint4*)(Afrag + idx) = pk;
    }
}

// ---------------- Kernel C: per (b,g,quarter): out_c = A[64x192] @ XT_c[192x64] via MFMA.
// No LDS: A-frags and B-frags are single 16B global loads (XT pre-transposed by prep).
__global__ __launch_bounds__(256) void inv_main_k(
    const u16* __restrict__ XT, const u16* __restrict__ Afrag,
    float* __restrict__ out)
{
    const int t = threadIdx.x, lane = t & 63, w = t >> 6;
    const int q = blockIdx.x & 3, bg = blockIdx.x >> 2;
    const int g = bg & 15, b = bg >> 4;
    const int ch = g * 16 + q * 4 + w;          // wave w -> its channel
    const int nl = lane & 15, quad = lane >> 4;

    f32x4 acc[4][4];
#pragma unroll
    for (int mt = 0; mt < 4; ++mt)
#pragma unroll
        for (int nt = 0; nt < 4; ++nt) acc[mt][nt] = (f32x4)0.f;

    const u16* XTc = XT + ((size_t)(b * CH + ch)) * HW;
#pragma unroll
    for (int ks = 0; ks < 6; ++ks) {
        const int d = ks >> 1, mh = ks & 1;
        const bf16x8* Ag = ((const bf16x8*)Afrag) + ((size_t)(bg * 6 + ks) * 4) * 64 + lane;
        bf16x8 a0 = Ag[0], a1 = Ag[64], a2 = Ag[128], a3 = Ag[192];
#pragma unroll
        for (int nt = 0; nt < 4; ++nt) {
            const int jrow = nt * 16 + nl + d - 1;
            const int jc = jrow < 0 ? 0 : (jrow > 63 ? 63 : jrow);
            bf16x8 bv = *(const bf16x8*)(XTc + jc * 64 + mh * 32 + quad * 8);
            if (jrow < 0 || jrow > 63) bv = (bf16x8)(short)0;
            acc[0][nt] = __builtin_amdgcn_mfma_f32_16x16x32_bf16(a0, bv, acc[0][nt], 0, 0, 0);
            acc[1][nt] = __builtin_amdgcn_mfma_f32_16x16x32_bf16(a1, bv, acc[1][nt], 0, 0, 0);
            acc[2][nt] = __builtin_amdgcn_mfma_f32_16x16x32_bf16(a2, bv, acc[2][nt], 0, 0, 0);
            acc[3][nt] = __builtin_amdgcn_mfma_f32_16x16x32_bf16(a3, bv, acc[3][nt], 0, 0, 0);
        }
    }
    // store (D layout: col = nl, row = quad*4+reg)
    float* op = out + ((size_t)(b * CH + ch)) * HW;
#pragma unroll
    for (int mt = 0; mt < 4; ++mt)
#pragma unroll
        for (int nt = 0; nt < 4; ++nt)
#pragma unroll
            for (int reg = 0; reg < 4; ++reg)
                op[(mt * 16 + quad * 4 + reg) * 64 + nt * 16 + nl] = acc[mt][nt][reg];
}

extern "C" void kernel_launch(void* const* d_in, const int* in_sizes, int n_in,
                              void* d_out, int out_size, void* d_ws, size_t ws_size,
                              hipStream_t stream)
{
    const float* x  = (const float*)d_in[0];
    const float* Wr = (const float*)d_in[1];   // (128,256)
    const float* br = (const float*)d_in[2];   // (128,)
    const float* Ws = (const float*)d_in[3];   // (144,128)
    const float* bs = (const float*)d_in[4];   // (144,)
    float* out = (float*)d_out;

    char* ws = (char*)d_ws;
    u16*   Mfrag = (u16*)(ws);                    // 73728 B
    float* biasF = (float*)(ws + 73728);          // 576 B
    u16*   Afrag = (u16*)(ws + 81920);            // 3145728 B
    u16*   Xc8   = (u16*)(ws + 3227648);          // 8*8*4096*32*2 = 16777216 B
    u16*   XT    = (u16*)(ws + 20004864);         // 8*256*4096*2  = 16777216 B

    fuse_weights_k<<<dim3(KKG), dim3(256), 0, stream>>>(Wr, br, Ws, bs, Mfrag, biasF);
    prep_k<<<dim3(512), dim3(256), 0, stream>>>(x, Xc8, XT);
    ker_abar_k<<<dim3(512), dim3(256), 0, stream>>>(Xc8, Mfrag, biasF, Afrag);  // 8 b * 64 rows
    inv_main_k<<<dim3(512), dim3(256), 0, stream>>>(XT, Afrag, out);            // 8 b*16 g*4 q
}

// Round 8
// 116.567 us; speedup vs baseline: 1.2149x; 1.2149x over previous
//
#include <hip/hip_runtime.h>

typedef unsigned short u16;
typedef unsigned int u32;
typedef __attribute__((ext_vector_type(8))) short bf16x8;   // 8 bf16 = 4 VGPR
typedef __attribute__((ext_vector_type(4))) float f32x4;

#define CH   256
#define KKG  144
#define HW   4096
#define CSP  68     // u16 stride for ker dump in LDS (64 + 4 pad)

__device__ __forceinline__ u16 f2bf(float f) {               // RNE float->bf16
    u32 u = __float_as_uint(f);
    u += 0x7FFFu + ((u >> 16) & 1u);
    return (u16)(u >> 16);
}
__device__ __forceinline__ float bf2f(u16 u) {
    return __uint_as_float(((u32)u) << 16);
}

// ---------------- Kernel A: Mfrag = bf16(W_span @ W_reduce) in A-frag-linear order
// Mfrag[ks(8)][mt(9)][lane(64)][8]; bias fused.
__global__ __launch_bounds__(256) void fuse_weights_k(
    const float* __restrict__ Wr, const float* __restrict__ br,
    const float* __restrict__ Ws, const float* __restrict__ bs,
    u16* __restrict__ Mfrag, float* __restrict__ biasF)
{
    __shared__ float ws[128];
    const int r = blockIdx.x;    // 0..143 (ker row)
    const int c = threadIdx.x;   // 0..255 (channel = K)
    if (c < 128) ws[c] = Ws[r * 128 + c];
    __syncthreads();
    float acc = 0.f;
#pragma unroll 8
    for (int o = 0; o < 128; ++o) acc += ws[o] * Wr[o * CH + c];
    const int ks = c >> 5, quad = (c >> 3) & 3, jj = c & 7;
    const int mt = r >> 4, lane = (r & 15) + (quad << 4);
    Mfrag[((ks * 9 + mt) * 64 + lane) * 8 + jj] = f2bf(acc);
    if (c == 0) {
        float bb = bs[r];
        for (int o = 0; o < 128; ++o) bb += ws[o] * br[o];
        biasF[r] = bb;
    }
}

// ---------------- Kernel B: per (b, image row): ker[144][64] = M @ X + bias via MFMA
// (B-frags gathered directly from global x), then ki-shift recombine ->
// Afrag[bg][ks(6)][mt(4)][lane][8]   (512 blocks -> 2 blocks/CU)
__global__ __launch_bounds__(256, 4) void ker_abar_k(
    const float* __restrict__ x, const u16* __restrict__ Mfrag,
    const float* __restrict__ biasF, u16* __restrict__ Afrag)
{
    __shared__ u16 Cs[KKG * CSP];      // 19584 B
    __shared__ float bias_s[KKG];
    const int b = blockIdx.x >> 6, irow = blockIdx.x & 63;
    const int t = threadIdx.x, lane = t & 63, w = t >> 6;
    const int nl = lane & 15, quad = lane >> 4;
    if (t < KKG) bias_s[t] = biasF[t];

    f32x4 acc[9];
#pragma unroll
    for (int mt = 0; mt < 9; ++mt) acc[mt] = (f32x4)0.f;

    const int ncol = irow * 64 + w * 16 + nl;   // spatial index
#pragma unroll
    for (int ks = 0; ks < 8; ++ks) {
        // B frag: k = ks*32 + quad*8 + j, col = ncol
        const float* xb = x + ((size_t)(b * CH + ks * 32 + quad * 8)) * HW + ncol;
        float f0 = xb[0],              f1 = xb[(size_t)HW],
              f2 = xb[2 * (size_t)HW], f3 = xb[3 * (size_t)HW],
              f4 = xb[4 * (size_t)HW], f5 = xb[5 * (size_t)HW],
              f6 = xb[6 * (size_t)HW], f7 = xb[7 * (size_t)HW];
        union { bf16x8 v; uint4 u; } bb;
        bb.u.x = (u32)f2bf(f0) | ((u32)f2bf(f1) << 16);
        bb.u.y = (u32)f2bf(f2) | ((u32)f2bf(f3) << 16);
        bb.u.z = (u32)f2bf(f4) | ((u32)f2bf(f5) << 16);
        bb.u.w = (u32)f2bf(f6) | ((u32)f2bf(f7) << 16);
        const bf16x8* Ag = ((const bf16x8*)Mfrag) + (ks * 9) * 64 + lane;
#pragma unroll
        for (int mt = 0; mt < 9; ++mt)
            acc[mt] = __builtin_amdgcn_mfma_f32_16x16x32_bf16(Ag[mt * 64], bb.v, acc[mt], 0, 0, 0);
    }
    __syncthreads();   // bias_s visible
    // dump ker = C + bias (D layout: col = lane&15, row = quad*4+reg)
#pragma unroll
    for (int mt = 0; mt < 9; ++mt) {
        const int rb = mt * 16 + quad * 4;
#pragma unroll
        for (int reg = 0; reg < 4; ++reg)
            Cs[(rb + reg) * CSP + w * 16 + nl] = f2bf(acc[mt][reg] + bias_s[rb + reg]);
    }
    __syncthreads();
    // Abar recombine + frag-linear store: 48 gd x 8 octs = 384 16B-chunks
    for (int v = t; v < 384; v += 256) {
        const int gd = v >> 3, o = v & 7;
        const int g = gd / 3, d = gd - g * 3;
        const int r0 = g * 9 + d;
        u16 h[8];
#pragma unroll
        for (int e = 0; e < 8; ++e) {
            const int m = o * 8 + e;
            float s = bf2f(Cs[(r0 + 3) * CSP + m]);            // ki=1
            if (m < 63) s += bf2f(Cs[r0 * CSP + m + 1]);       // ki=0 -> col+1
            if (m > 0)  s += bf2f(Cs[(r0 + 6) * CSP + m - 1]); // ki=2 -> col-1
            h[e] = f2bf(s);
        }
        uint4 pk;
        pk.x = (u32)h[0] | ((u32)h[1] << 16);
        pk.y = (u32)h[2] | ((u32)h[3] << 16);
        pk.z = (u32)h[4] | ((u32)h[5] << 16);
        pk.w = (u32)h[6] | ((u32)h[7] << 16);
        const int ks2 = 2 * d + (o >> 2), quad2 = o & 3;
        const int mt2 = irow >> 4, lane2 = (irow & 15) + (quad2 << 4);
        const size_t idx = ((((size_t)(b * 16 + g) * 6 + ks2) * 4 + mt2) * 64 + lane2) * 8;
        *(uint4*)(Afrag + idx) = pk;
    }
}

// ---------------- Kernel C: per (b,g,quarter): out_c = Aall[64x192] @ XTc[192x64] via MFMA.
// XT[j][m] (bf16, XOR-swizzled 16B chunks) built per channel in LDS; A-frags from global.
__global__ __launch_bounds__(256) void inv_main_k(
    const float* __restrict__ x, const u16* __restrict__ Afrag,
    float* __restrict__ out)
{
    __shared__ u16 XT[4 * 4096];   // 32 KB: 4 channels, chunk(j,o) = j*8 + (o^(j&7))
    const int t = threadIdx.x;
    const int q = blockIdx.x & 3, bg = blockIdx.x >> 2;
    const int g = bg & 15, b = bg >> 4;
    const int ch_base = g * 16 + q * 4;

    // staging: 4 ch x 8 octs x 16 j-quads = 512 tasks (jq fastest for coalescing)
    for (int task = t; task < 512; task += 256) {
        const int ch = task >> 7, rem = task & 127;
        const int o = rem >> 4, jq = rem & 15;
        const float* xc = x + ((size_t)(b * CH + ch_base + ch)) * HW + o * 512 + jq * 4;
        float4 r0 = *(const float4*)(xc);
        float4 r1 = *(const float4*)(xc + 64);
        float4 r2 = *(const float4*)(xc + 128);
        float4 r3 = *(const float4*)(xc + 192);
        float4 r4 = *(const float4*)(xc + 256);
        float4 r5 = *(const float4*)(xc + 320);
        float4 r6 = *(const float4*)(xc + 384);
        float4 r7 = *(const float4*)(xc + 448);
        u16* base = XT + ch * 4096;
        uint4 pk;
        int j, chunk;
        pk.x = (u32)f2bf(r0.x) | ((u32)f2bf(r1.x) << 16);
        pk.y = (u32)f2bf(r2.x) | ((u32)f2bf(r3.x) << 16);
        pk.z = (u32)f2bf(r4.x) | ((u32)f2bf(r5.x) << 16);
        pk.w = (u32)f2bf(r6.x) | ((u32)f2bf(r7.x) << 16);
        j = jq * 4 + 0; chunk = j * 8 + (o ^ (j & 7));
        *(uint4*)(base + chunk * 8) = pk;
        pk.x = (u32)f2bf(r0.y) | ((u32)f2bf(r1.y) << 16);
        pk.y = (u32)f2bf(r2.y) | ((u32)f2bf(r3.y) << 16);
        pk.z = (u32)f2bf(r4.y) | ((u32)f2bf(r5.y) << 16);
        pk.w = (u32)f2bf(r6.y) | ((u32)f2bf(r7.y) << 16);
        j = jq * 4 + 1; chunk = j * 8 + (o ^ (j & 7));
        *(uint4*)(base + chunk * 8) = pk;
        pk.x = (u32)f2bf(r0.z) | ((u32)f2bf(r1.z) << 16);
        pk.y = (u32)f2bf(r2.z) | ((u32)f2bf(r3.z) << 16);
        pk.z = (u32)f2bf(r4.z) | ((u32)f2bf(r5.z) << 16);
        pk.w = (u32)f2bf(r6.z) | ((u32)f2bf(r7.z) << 16);
        j = jq * 4 + 2; chunk = j * 8 + (o ^ (j & 7));
        *(uint4*)(base + chunk * 8) = pk;
        pk.x = (u32)f2bf(r0.w) | ((u32)f2bf(r1.w) << 16);
        pk.y = (u32)f2bf(r2.w) | ((u32)f2bf(r3.w) << 16);
        pk.z = (u32)f2bf(r4.w) | ((u32)f2bf(r5.w) << 16);
        pk.w = (u32)f2bf(r6.w) | ((u32)f2bf(r7.w) << 16);
        j = jq * 4 + 3; chunk = j * 8 + (o ^ (j & 7));
        *(uint4*)(base + chunk * 8) = pk;
    }
    __syncthreads();

    const int lane = t & 63, w = t >> 6;     // wave w -> local channel w
    const int nl = lane & 15, quad = lane >> 4;
    f32x4 acc[4][4];
#pragma unroll
    for (int mt = 0; mt < 4; ++mt)
#pragma unroll
        for (int nt = 0; nt < 4; ++nt) acc[mt][nt] = (f32x4)0.f;

    const u16* XTc = XT + w * 4096;
#pragma unroll
    for (int ks = 0; ks < 6; ++ks) {
        const int d = ks >> 1, mh = ks & 1;
        const bf16x8* Ag = ((const bf16x8*)Afrag) + ((size_t)(bg * 6 + ks) * 4) * 64 + lane;
        bf16x8 a0 = Ag[0], a1 = Ag[64], a2 = Ag[128], a3 = Ag[192];
        const int o = mh * 4 + quad;
#pragma unroll
        for (int nt = 0; nt < 4; ++nt) {
            const int jrow = nt * 16 + nl + d - 1;
            const int jc = jrow < 0 ? 0 : (jrow > 63 ? 63 : jrow);
            const int chunk = jc * 8 + (o ^ (jc & 7));
            bf16x8 bv = *(const bf16x8*)(XTc + chunk * 8);
            if (jrow < 0 || jrow > 63) bv = (bf16x8)(short)0;
            acc[0][nt] = __builtin_amdgcn_mfma_f32_16x16x32_bf16(a0, bv, acc[0][nt], 0, 0, 0);
            acc[1][nt] = __builtin_amdgcn_mfma_f32_16x16x32_bf16(a1, bv, acc[1][nt], 0, 0, 0);
            acc[2][nt] = __builtin_amdgcn_mfma_f32_16x16x32_bf16(a2, bv, acc[2][nt], 0, 0, 0);
            acc[3][nt] = __builtin_amdgcn_mfma_f32_16x16x32_bf16(a3, bv, acc[3][nt], 0, 0, 0);
        }
    }
    // store (D layout: col = nl, row = quad*4+reg)
    float* op = out + ((size_t)(b * CH + ch_base + w)) * HW;
#pragma unroll
    for (int mt = 0; mt < 4; ++mt)
#pragma unroll
        for (int nt = 0; nt < 4; ++nt)
#pragma unroll
            for (int reg = 0; reg < 4; ++reg)
                op[(mt * 16 + quad * 4 + reg) * 64 + nt * 16 + nl] = acc[mt][nt][reg];
}

extern "C" void kernel_launch(void* const* d_in, const int* in_sizes, int n_in,
                              void* d_out, int out_size, void* d_ws, size_t ws_size,
                              hipStream_t stream)
{
    const float* x  = (const float*)d_in[0];
    const float* Wr = (const float*)d_in[1];   // (128,256)
    const float* br = (const float*)d_in[2];   // (128,)
    const float* Ws = (const float*)d_in[3];   // (144,128)
    const float* bs = (const float*)d_in[4];   // (144,)
    float* out = (float*)d_out;

    char* ws = (char*)d_ws;
    u16*   Mfrag = (u16*)(ws);                 // 8*9*64*8*2 = 73728 B
    float* biasF = (float*)(ws + 73728);       // 576 B
    u16*   Afrag = (u16*)(ws + 81920);         // 128*6*4*64*8*2 = 3145728 B

    fuse_weights_k<<<dim3(KKG), dim3(256), 0, stream>>>(Wr, br, Ws, bs, Mfrag, biasF);
    ker_abar_k<<<dim3(512), dim3(256), 0, stream>>>(x, Mfrag, biasF, Afrag);   // 8 b * 64 rows
    inv_main_k<<<dim3(512), dim3(256), 0, stream>>>(x, Afrag, out);            // 8 b * 16 g * 4 q
}

// Round 9
// 112.822 us; speedup vs baseline: 1.2553x; 1.0332x over previous
//
#include <hip/hip_runtime.h>

typedef unsigned short u16;
typedef unsigned int u32;
typedef __attribute__((ext_vector_type(8))) short bf16x8;   // 8 bf16 = 4 VGPR
typedef __attribute__((ext_vector_type(4))) float f32x4;

#define CH   256
#define KKG  144
#define HW   4096
#define CSP  132    // u16 stride for epilogue ker dump in LDS

__device__ __forceinline__ u16 f2bf(float f) {               // RNE float->bf16
    u32 u = __float_as_uint(f);
    u += 0x7FFFu + ((u >> 16) & 1u);
    return (u16)(u >> 16);
}
__device__ __forceinline__ float bf2f(u16 u) {
    return __uint_as_float(((u32)u) << 16);
}

// ---------------- Kernel A: M = W_span @ W_reduce (144x256) written in MFMA
// A-fragment-linear order Mfrag[ks(8)][mt(9)][lane(64)][8]; bias fused.
__global__ __launch_bounds__(256) void fuse_weights_k(
    const float* __restrict__ Wr, const float* __restrict__ br,
    const float* __restrict__ Ws, const float* __restrict__ bs,
    u16* __restrict__ Mfrag, float* __restrict__ biasF)
{
    __shared__ float ws[128];
    const int r = blockIdx.x;    // 0..143 (ker row)
    const int c = threadIdx.x;   // 0..255 (channel = K)
    if (c < 128) ws[c] = Ws[r * 128 + c];
    __syncthreads();
    float acc = 0.f;
#pragma unroll 8
    for (int o = 0; o < 128; ++o) acc += ws[o] * Wr[o * CH + c];
    const int ks = c >> 5, quad = (c >> 3) & 3, jj = c & 7;
    const int mt = r >> 4, lane = (r & 15) + (quad << 4);
    Mfrag[((ks * 9 + mt) * 64 + lane) * 8 + jj] = f2bf(acc);
    if (c == 0) {
        float bb = bs[r];
        for (int o = 0; o < 128; ++o) bb += ws[o] * br[o];
        biasF[r] = bb;
    }
}

// ---------------- Kernel B: per (b, 2 image rows): ker[144][128] = M @ X + bias via MFMA
// (B-frags gathered directly from global x, no LDS/barriers in K-loop), then the
// ki-shift recombine writes Abar in A-fragment-linear order: Afrag[bg][ks(6)][mt(4)][lane][8]
__global__ __launch_bounds__(256) void ker_abar_k(
    const float* __restrict__ x, const u16* __restrict__ Mfrag,
    const float* __restrict__ biasF, u16* __restrict__ Afrag)
{
    __shared__ u16 Cs[KKG * CSP];      // 38016 B
    __shared__ float bias_s[KKG];
    const int b = blockIdx.x >> 5, jt = blockIdx.x & 31;
    const int col0 = jt * 128;
    const int t = threadIdx.x, lane = t & 63, w = t >> 6;
    const int nl = lane & 15, quad = lane >> 4;
    if (t < KKG) bias_s[t] = biasF[t];

    f32x4 acc[9][2];
#pragma unroll
    for (int mt = 0; mt < 9; ++mt)
#pragma unroll
        for (int nt = 0; nt < 2; ++nt) acc[mt][nt] = (f32x4)0.f;

    const int n0 = col0 + w * 32;
    for (int ks = 0; ks < 8; ++ks) {
        bf16x8 a[9];
        const bf16x8* Ag = ((const bf16x8*)Mfrag) + (ks * 9) * 64 + lane;
#pragma unroll
        for (int mt = 0; mt < 9; ++mt) a[mt] = Ag[mt * 64];
#pragma unroll
        for (int nt = 0; nt < 2; ++nt) {
            const float* xb = x + ((size_t)(b * CH + ks * 32 + quad * 8)) * HW + n0 + nt * 16 + nl;
            float f0 = xb[0],        f1 = xb[(size_t)HW],
                  f2 = xb[2*(size_t)HW], f3 = xb[3*(size_t)HW],
                  f4 = xb[4*(size_t)HW], f5 = xb[5*(size_t)HW],
                  f6 = xb[6*(size_t)HW], f7 = xb[7*(size_t)HW];
            union { bf16x8 v; uint4 u; } bb;
            bb.u.x = (u32)f2bf(f0) | ((u32)f2bf(f1) << 16);
            bb.u.y = (u32)f2bf(f2) | ((u32)f2bf(f3) << 16);
            bb.u.z = (u32)f2bf(f4) | ((u32)f2bf(f5) << 16);
            bb.u.w = (u32)f2bf(f6) | ((u32)f2bf(f7) << 16);
#pragma unroll
            for (int mt = 0; mt < 9; ++mt)
                acc[mt][nt] = __builtin_amdgcn_mfma_f32_16x16x32_bf16(a[mt], bb.v, acc[mt][nt], 0, 0, 0);
        }
    }
    __syncthreads();   // bias_s visible; Cs about to be written
    // dump ker = C + bias (D layout: col = lane&15, row = quad*4+reg)
#pragma unroll
    for (int mt = 0; mt < 9; ++mt)
#pragma unroll
        for (int nt = 0; nt < 2; ++nt) {
            const int colb = w * 32 + nt * 16 + nl;
            const int rb = mt * 16 + quad * 4;
#pragma unroll
            for (int reg = 0; reg < 4; ++reg)
                Cs[(rb + reg) * CSP + colb] = f2bf(acc[mt][nt][reg] + bias_s[rb + reg]);
        }
    __syncthreads();
    // Abar recombine + frag-linear store: 48 gd x 2 rows x 8 octs = 768 16B-chunks
    for (int v = t; v < 768; v += 256) {
        const int gd = v >> 4, rem = v & 15;
        const int il = rem >> 3, o = rem & 7;
        const int g = gd / 3, d = gd - g * 3;
        const int r0 = g * 9 + d;
        const int i = jt * 2 + il;          // image row 0..63
        const int base = il * 64 + o * 8;   // col base within Cs row
        u16 h[8];
#pragma unroll
        for (int e = 0; e < 8; ++e) {
            const int m = o * 8 + e;
            float s = bf2f(Cs[(r0 + 3) * CSP + base + e]);            // ki=1
            if (m < 63) s += bf2f(Cs[r0 * CSP + base + e + 1]);       // ki=0 -> col+1
            if (m > 0)  s += bf2f(Cs[(r0 + 6) * CSP + base + e - 1]); // ki=2 -> col-1
            h[e] = f2bf(s);
        }
        uint4 pk;
        pk.x = (u32)h[0] | ((u32)h[1] << 16);
        pk.y = (u32)h[2] | ((u32)h[3] << 16);
        pk.z = (u32)h[4] | ((u32)h[5] << 16);
        pk.w = (u32)h[6] | ((u32)h[7] << 16);
        const int ks2 = 2 * d + (o >> 2), quad2 = o & 3;
        const int mt2 = i >> 4, lane2 = (i & 15) + (quad2 << 4);
        const size_t idx = ((((size_t)(b * 16 + g) * 6 + ks2) * 4 + mt2) * 64 + lane2) * 8;
        *(uint4*)(Afrag + idx) = pk;
    }
}

// ---------------- Kernel C: per (b,g,quarter): out_c = Aall[64x192] @ XTc[192x64] via MFMA.
// XT[j][m] (bf16, XOR-swizzled 16B chunks) built per channel in LDS; A-frags from global.
__global__ __launch_bounds__(256) void inv_main_k(
    const float* __restrict__ x, const u16* __restrict__ Afrag,
    float* __restrict__ out)
{
    __shared__ u16 XT[4 * 4096];   // 32 KB: 4 channels, chunk(j,o) = j*8 + (o^(j&7))
    const int t = threadIdx.x;
    const int q = blockIdx.x & 3, bg = blockIdx.x >> 2;
    const int g = bg & 15, b = bg >> 4;
    const int ch_base = g * 16 + q * 4;

    // staging: 4 ch x 8 octs x 16 j-quads = 512 tasks (jq fastest for coalescing)
    for (int task = t; task < 512; task += 256) {
        const int ch = task >> 7, rem = task & 127;
        const int o = rem >> 4, jq = rem & 15;
        const float* xc = x + ((size_t)(b * CH + ch_base + ch)) * HW + o * 512 + jq * 4;
        float4 r0 = *(const float4*)(xc);
        float4 r1 = *(const float4*)(xc + 64);
        float4 r2 = *(const float4*)(xc + 128);
        float4 r3 = *(const float4*)(xc + 192);
        float4 r4 = *(const float4*)(xc + 256);
        float4 r5 = *(const float4*)(xc + 320);
        float4 r6 = *(const float4*)(xc + 384);
        float4 r7 = *(const float4*)(xc + 448);
        u16* base = XT + ch * 4096;
        uint4 pk;
        int j, chunk;
        pk.x = (u32)f2bf(r0.x) | ((u32)f2bf(r1.x) << 16);
        pk.y = (u32)f2bf(r2.x) | ((u32)f2bf(r3.x) << 16);
        pk.z = (u32)f2bf(r4.x) | ((u32)f2bf(r5.x) << 16);
        pk.w = (u32)f2bf(r6.x) | ((u32)f2bf(r7.x) << 16);
        j = jq * 4 + 0; chunk = j * 8 + (o ^ (j & 7));
        *(uint4*)(base + chunk * 8) = pk;
        pk.x = (u32)f2bf(r0.y) | ((u32)f2bf(r1.y) << 16);
        pk.y = (u32)f2bf(r2.y) | ((u32)f2bf(r3.y) << 16);
        pk.z = (u32)f2bf(r4.y) | ((u32)f2bf(r5.y) << 16);
        pk.w = (u32)f2bf(r6.y) | ((u32)f2bf(r7.y) << 16);
        j = jq * 4 + 1; chunk = j * 8 + (o ^ (j & 7));
        *(uint4*)(base + chunk * 8) = pk;
        pk.x = (u32)f2bf(r0.z) | ((u32)f2bf(r1.z) << 16);
        pk.y = (u32)f2bf(r2.z) | ((u32)f2bf(r3.z) << 16);
        pk.z = (u32)f2bf(r4.z) | ((u32)f2bf(r5.z) << 16);
        pk.w = (u32)f2bf(r6.z) | ((u32)f2bf(r7.z) << 16);
        j = jq * 4 + 2; chunk = j * 8 + (o ^ (j & 7));
        *(uint4*)(base + chunk * 8) = pk;
        pk.x = (u32)f2bf(r0.w) | ((u32)f2bf(r1.w) << 16);
        pk.y = (u32)f2bf(r2.w) | ((u32)f2bf(r3.w) << 16);
        pk.z = (u32)f2bf(r4.w) | ((u32)f2bf(r5.w) << 16);
        pk.w = (u32)f2bf(r6.w) | ((u32)f2bf(r7.w) << 16);
        j = jq * 4 + 3; chunk = j * 8 + (o ^ (j & 7));
        *(uint4*)(base + chunk * 8) = pk;
    }
    __syncthreads();

    const int lane = t & 63, w = t >> 6;     // wave w -> local channel w
    const int nl = lane & 15, quad = lane >> 4;
    f32x4 acc[4][4];
#pragma unroll
    for (int mt = 0; mt < 4; ++mt)
#pragma unroll
        for (int nt = 0; nt < 4; ++nt) acc[mt][nt] = (f32x4)0.f;

    const u16* XTc = XT + w * 4096;
#pragma unroll
    for (int ks = 0; ks < 6; ++ks) {
        const int d = ks >> 1, mh = ks & 1;
        const bf16x8* Ag = ((const bf16x8*)Afrag) + ((size_t)(bg * 6 + ks) * 4) * 64 + lane;
        bf16x8 a0 = Ag[0], a1 = Ag[64], a2 = Ag[128], a3 = Ag[192];
        const int o = mh * 4 + quad;
#pragma unroll
        for (int nt = 0; nt < 4; ++nt) {
            const int jrow = nt * 16 + nl + d - 1;
            const int jc = jrow < 0 ? 0 : (jrow > 63 ? 63 : jrow);
            const int chunk = jc * 8 + (o ^ (jc & 7));
            bf16x8 bv = *(const bf16x8*)(XTc + chunk * 8);
            if (jrow < 0 || jrow > 63) bv = (bf16x8)(short)0;
            acc[0][nt] = __builtin_amdgcn_mfma_f32_16x16x32_bf16(a0, bv, acc[0][nt], 0, 0, 0);
            acc[1][nt] = __builtin_amdgcn_mfma_f32_16x16x32_bf16(a1, bv, acc[1][nt], 0, 0, 0);
            acc[2][nt] = __builtin_amdgcn_mfma_f32_16x16x32_bf16(a2, bv, acc[2][nt], 0, 0, 0);
            acc[3][nt] = __builtin_amdgcn_mfma_f32_16x16x32_bf16(a3, bv, acc[3][nt], 0, 0, 0);
        }
    }
    // store (D layout: col = nl, row = quad*4+reg)
    float* op = out + ((size_t)(b * CH + ch_base + w)) * HW;
#pragma unroll
    for (int mt = 0; mt < 4; ++mt)
#pragma unroll
        for (int nt = 0; nt < 4; ++nt)
#pragma unroll
            for (int reg = 0; reg < 4; ++reg)
                op[(mt * 16 + quad * 4 + reg) * 64 + nt * 16 + nl] = acc[mt][nt][reg];
}

extern "C" void kernel_launch(void* const* d_in, const int* in_sizes, int n_in,
                              void* d_out, int out_size, void* d_ws, size_t ws_size,
                              hipStream_t stream)
{
    const float* x  = (const float*)d_in[0];
    const float* Wr = (const float*)d_in[1];   // (128,256)
    const float* br = (const float*)d_in[2];   // (128,)
    const float* Ws = (const float*)d_in[3];   // (144,128)
    const float* bs = (const float*)d_in[4];   // (144,)
    float* out = (float*)d_out;

    char* ws = (char*)d_ws;
    u16*   Mfrag = (u16*)(ws);                 // 8*9*64*8*2 = 73728 B
    float* biasF = (float*)(ws + 73728);       // 576 B
    u16*   Afrag = (u16*)(ws + 81920);         // 128*6*4*64*8*2 = 3145728 B

    fuse_weights_k<<<dim3(KKG), dim3(256), 0, stream>>>(Wr, br, Ws, bs, Mfrag, biasF);
    ker_abar_k<<<dim3(256), dim3(256), 0, stream>>>(x, Mfrag, biasF, Afrag);   // 8 b * 32 row-pairs
    inv_main_k<<<dim3(512), dim3(256), 0, stream>>>(x, Afrag, out);            // 8 b * 16 g * 4 quarters
}